// Round 6
// baseline (6102.409 us; speedup 1.0000x reference)
//
#include <hip/hip_runtime.h>
#include <hip/hip_cooperative_groups.h>
#include <cstdint>
#include <cstddef>

namespace cg = cooperative_groups;

#define BATCH 4096
#define DIM 64
#define HID 512
#define NPER 2048
#define KEV 25
#define NBLK 256
#define NTHR 512
#define DT_C 0.01f
#define LOG_SQRT_2PI_C 0.9189385332046727f

typedef __attribute__((ext_vector_type(8))) short short8;
typedef __attribute__((ext_vector_type(4))) float f32x4;

#define MFMA(a, b, c) __builtin_amdgcn_mfma_f32_16x16x32_bf16(a, b, c, 0, 0, 0)

__device__ __forceinline__ ushort f2bf(float f) {
    uint32_t u = __float_as_uint(f);
    u += 0x7FFF + ((u >> 16) & 1);
    return (ushort)(u >> 16);
}
__device__ __forceinline__ float sigmoidf_(float x) { return 1.0f / (1.0f + expf(-x)); }

// B fragment direct from global (row-major, leading dim ldb)
__device__ __forceinline__ short8 bglob(const ushort* B, int col, int ldb, int k0, int ks, int lane) {
    int slot = (ks << 2) + (lane >> 4);
    return *(const short8*)&B[(size_t)col * ldb + k0 + slot * 8];
}
// A fragment from [128][64] LDS tile, XOR-swizzled 8-elem slots
__device__ __forceinline__ short8 frag64(const ushort* lds, int row, int ks, int lane) {
    int slot = ((ks << 2) + (lane >> 4)) ^ (row & 7);
    return *(const short8*)&lds[row * 64 + slot * 8];
}
// A fragment from [16][512] LDS tile, XOR-swizzled 8-elem slots
__device__ __forceinline__ short8 frag512(const ushort* lds, int row, int t, int ks, int lane) {
    int q = t * 8 + (ks << 2) + (lane >> 4);
    return *(const short8*)&lds[row * 512 + ((q ^ (row & 7)) << 3)];
}

// p = relu-head output GEMM fused with NLL loss; task = 128 rows x 128 cols
__device__ void p_loss_task(
    int ke, int bid, ushort* tbuf,
    const ushort* qb, const ushort* Wp2, const float* bp2,
    const float* Xf, const float* Mf, float* sums,
    int tid, int lane, int w)
{
    const int r0t = bid * 128;
    const int q0 = tid * 2;
    const int arow = q0 >> 3;
    const int as0 = q0 & 7;
    const size_t ga = (size_t)(r0t + arow) * HID;
    const float* Xk = Xf + (size_t)ke * NPER * DIM;
    const float* Mk = Mf + (size_t)ke * NPER * DIM;

    f32x4 acc[8] = {};
    short8 ld0 = *(const short8*)&qb[ga + as0 * 8];
    short8 ld1 = *(const short8*)&qb[ga + as0 * 8 + 8];
    for (int t = 0; t < 8; ++t) {
        __syncthreads();
        *(short8*)&tbuf[arow * 64 + ((as0 ^ (arow & 7)) << 3)] = ld0;
        *(short8*)&tbuf[arow * 64 + (((as0 + 1) ^ (arow & 7)) << 3)] = ld1;
        __syncthreads();
        if (t < 7) {
            ld0 = *(const short8*)&qb[ga + (t + 1) * 64 + as0 * 8];
            ld1 = *(const short8*)&qb[ga + (t + 1) * 64 + as0 * 8 + 8];
        }
        int row = w * 16 + (lane & 15);
        short8 a0 = frag64(tbuf, row, 0, lane);
        short8 a1 = frag64(tbuf, row, 1, lane);
        #pragma unroll
        for (int ni = 0; ni < 8; ++ni) {
            int c = ni * 16 + (lane & 15);
            short8 g0 = bglob(Wp2, c, HID, t * 64, 0, lane);
            short8 g1 = bglob(Wp2, c, HID, t * 64, 1, lane);
            acc[ni] = MFMA(a0, g0, acc[ni]);
            acc[ni] = MFMA(a1, g1, acc[ni]);
        }
    }
    float ls = 0.0f;
    #pragma unroll
    for (int ni = 0; ni < 4; ++ni) {
        int j = ni * 16 + (lane & 15);
        float bm = bp2[j], bl = bp2[64 + j];
        #pragma unroll
        for (int ii = 0; ii < 4; ++ii) {
            int row = r0t + w * 16 + ((lane >> 4) << 2) + ii;
            float mean = acc[ni][ii] + bm;
            float lv   = acc[ni + 4][ii] + bl;
            float xo = Xk[(size_t)row * DIM + j];
            float mo = Mk[(size_t)row * DIM + j];
            float err = (xo - mean) * expf(-0.5f * lv);
            ls += 0.5f * (err * err + lv + 2.0f * LOG_SQRT_2PI_C) * mo;
        }
    }
    #pragma unroll
    for (int o = 32; o > 0; o >>= 1) ls += __shfl_down(ls, o);
    if (lane == 0) atomicAdd(sums, ls);
}

__global__ __launch_bounds__(NTHR, 2) void persist(
    const float* __restrict__ Xf, const float* __restrict__ Mf,
    const int* __restrict__ bidx, const ushort* __restrict__ Xb,
    const ushort* __restrict__ W1, const ushort* __restrict__ W2,
    const ushort* __restrict__ Wp1, const ushort* __restrict__ Wp2,
    const ushort* __restrict__ Wih, const ushort* __restrict__ Whh,
    const float* __restrict__ b1, const float* __restrict__ b2,
    const float* __restrict__ bih, const float* __restrict__ bhh,
    const float* __restrict__ bp1, const float* __restrict__ bp2,
    float* __restrict__ h, ushort* __restrict__ hb,
    ushort* __restrict__ qb, float* __restrict__ sums, float* __restrict__ out)
{
    __shared__ __align__(16) float  h_loc[16 * 512];   // 32 KB fp32 master (own rows)
    __shared__ __align__(16) ushort hbloc[16 * 512];   // 16 KB bf16 shadow (swizzled)
    __shared__ __align__(16) ushort tbuf[16 * 512];    // 16 KB: ODE tanh-T / event A-tile
    cg::grid_group grid = cg::this_grid();
    const int tid = threadIdx.x, lane = tid & 63, w = tid >> 6;
    const int bid = blockIdx.x;
    const int r0 = bid * 16;

    // phase 0: m_tot (grid-stride, wave atomics)
    {
        float v = 0.0f;
        const float4* M4 = (const float4*)Mf;
        const int n4 = KEV * NPER * DIM / 4;
        for (int t = bid * NTHR + tid; t < n4; t += NBLK * NTHR) {
            float4 x = M4[t]; v += x.x + x.y + x.z + x.w;
        }
        #pragma unroll
        for (int o = 32; o > 0; o >>= 1) v += __shfl_down(v, o);
        if (lane == 0) atomicAdd(sums + 1, v);
    }

    for (int k = 0; k < KEV; ++k) {
        // ---- load own h rows into LDS (fp32 + swizzled bf16 shadow) ----
        #pragma unroll
        for (int i = 0; i < 4; ++i) {
            int c = tid + i * NTHR;                 // float4 id 0..2047
            float4 v = *(const float4*)&h[(size_t)r0 * HID + (size_t)c * 4];
            *(float4*)&h_loc[c * 4] = v;
            int row = c >> 7, e = (c & 127) * 4;
            int sl = (e >> 3) ^ (row & 7);
            ushort4 o4 = {f2bf(v.x), f2bf(v.y), f2bf(v.z), f2bf(v.w)};
            *(ushort4*)&hbloc[row * 512 + sl * 8 + (e & 7)] = o4;
        }
        __syncthreads();

        // ---- 2 Euler steps, fully row-local (no grid syncs) ----
        const int cw0 = w * 64;
        for (int s = 0; s < 2; ++s) {
            // T = tanh(hb_loc @ W1^T + b1)
            f32x4 acc[4] = {};
            for (int t = 0; t < 8; ++t) {
                short8 a0 = frag512(hbloc, lane & 15, t, 0, lane);
                short8 a1 = frag512(hbloc, lane & 15, t, 1, lane);
                #pragma unroll
                for (int ni = 0; ni < 4; ++ni) {
                    int c = cw0 + ni * 16 + (lane & 15);
                    short8 g0 = bglob(W1, c, HID, t * 64, 0, lane);
                    short8 g1 = bglob(W1, c, HID, t * 64, 1, lane);
                    acc[ni] = MFMA(a0, g0, acc[ni]);
                    acc[ni] = MFMA(a1, g1, acc[ni]);
                }
            }
            #pragma unroll
            for (int ni = 0; ni < 4; ++ni) {
                int c = cw0 + ni * 16 + (lane & 15);
                float bv = b1[c];
                #pragma unroll
                for (int ii = 0; ii < 4; ++ii) {
                    int r = ((lane >> 4) << 2) + ii;
                    float tv = tanhf(acc[ni][ii] + bv);
                    tbuf[r * 512 + (((c >> 3) ^ (r & 7)) << 3) + (c & 7)] = f2bf(tv);
                }
            }
            __syncthreads();
            // h_loc += DT*(T @ W2^T + b2); refresh shadow
            f32x4 ac2[4] = {};
            for (int t = 0; t < 8; ++t) {
                short8 a0 = frag512(tbuf, lane & 15, t, 0, lane);
                short8 a1 = frag512(tbuf, lane & 15, t, 1, lane);
                #pragma unroll
                for (int ni = 0; ni < 4; ++ni) {
                    int c = cw0 + ni * 16 + (lane & 15);
                    short8 g0 = bglob(W2, c, HID, t * 64, 0, lane);
                    short8 g1 = bglob(W2, c, HID, t * 64, 1, lane);
                    ac2[ni] = MFMA(a0, g0, ac2[ni]);
                    ac2[ni] = MFMA(a1, g1, ac2[ni]);
                }
            }
            #pragma unroll
            for (int ni = 0; ni < 4; ++ni) {
                int c = cw0 + ni * 16 + (lane & 15);
                float bv = b2[c];
                #pragma unroll
                for (int ii = 0; ii < 4; ++ii) {
                    int r = ((lane >> 4) << 2) + ii;
                    float nh = h_loc[r * 512 + c] + DT_C * (ac2[ni][ii] + bv);
                    h_loc[r * 512 + c] = nh;
                    hbloc[r * 512 + (((c >> 3) ^ (r & 7)) << 3) + (c & 7)] = f2bf(nh);
                }
            }
            __syncthreads();
        }

        // ---- write h, hb to global ----
        #pragma unroll
        for (int i = 0; i < 4; ++i) {
            int c = tid + i * NTHR;
            *(float4*)&h[(size_t)r0 * HID + (size_t)c * 4] = *(const float4*)&h_loc[c * 4];
        }
        #pragma unroll
        for (int cc = 0; cc < 2; ++cc) {
            int q = tid * 2 + cc;
            int r = q >> 6, sp = q & 63;
            *(float4*)&hb[(size_t)(r0 + r) * HID + sp * 8] =
                *(const float4*)&hbloc[r * 512 + ((sp ^ (r & 7)) << 3)];
        }
        __syncthreads();

        // overlap: previous event's p+loss on 16 blocks (tbuf is free now)
        if (k > 0 && bid < 16)
            p_loss_task(k - 1, bid, tbuf, qb, Wp2, bp2, Xf, Mf, sums, tid, lane, w);

        grid.sync();

        // ---- E1: GRU (bid<128) / q-head (bid>=128), 256 tasks == grid ----
        const ushort* Xbk = Xb + (size_t)k * NPER * DIM;
        const int* idxk = bidx + (size_t)k * NPER;
        {
            const bool isGRU = bid < 128;
            const int tb = isGRU ? bid : bid - 128;
            const int r0t = (tb >> 3) * 128, c0 = (tb & 7) * 64;
            const int q0 = tid * 2;
            const int arow = q0 >> 3;
            const int as0 = q0 & 7;
            const int obsrow = r0t + arow;
            const size_t ga = (size_t)idxk[obsrow] * HID;
            const int wr = w >> 2, wc = w & 3;   // 2 row-groups x 4 col-groups
            const int NT = isGRU ? 9 : 8;

            f32x4 aR[4] = {}, aZ[4] = {}, aNh[4] = {}, aNx[4] = {};
            short8 ld0 = *(const short8*)&hb[ga + as0 * 8];
            short8 ld1 = *(const short8*)&hb[ga + as0 * 8 + 8];
            const int cB = c0 + wc * 16 + (lane & 15);
            for (int t = 0; t < NT; ++t) {
                __syncthreads();
                *(short8*)&tbuf[arow * 64 + ((as0 ^ (arow & 7)) << 3)] = ld0;
                *(short8*)&tbuf[arow * 64 + (((as0 + 1) ^ (arow & 7)) << 3)] = ld1;
                __syncthreads();
                if (t + 1 < NT) {
                    if (t + 1 < 8) {
                        ld0 = *(const short8*)&hb[ga + (t + 1) * 64 + as0 * 8];
                        ld1 = *(const short8*)&hb[ga + (t + 1) * 64 + as0 * 8 + 8];
                    } else {
                        ld0 = *(const short8*)&Xbk[(size_t)obsrow * DIM + as0 * 8];
                        ld1 = *(const short8*)&Xbk[(size_t)obsrow * DIM + as0 * 8 + 8];
                    }
                }
                short8 af[4][2];
                #pragma unroll
                for (int mi = 0; mi < 4; ++mi) {
                    int row = wr * 64 + mi * 16 + (lane & 15);
                    af[mi][0] = frag64(tbuf, row, 0, lane);
                    af[mi][1] = frag64(tbuf, row, 1, lane);
                }
                if (isGRU) {
                    if (t < 8) {
                        short8 bR0 = bglob(Whh, cB, HID, t * 64, 0, lane);
                        short8 bR1 = bglob(Whh, cB, HID, t * 64, 1, lane);
                        short8 bZ0 = bglob(Whh, 512 + cB, HID, t * 64, 0, lane);
                        short8 bZ1 = bglob(Whh, 512 + cB, HID, t * 64, 1, lane);
                        short8 bN0 = bglob(Whh, 1024 + cB, HID, t * 64, 0, lane);
                        short8 bN1 = bglob(Whh, 1024 + cB, HID, t * 64, 1, lane);
                        #pragma unroll
                        for (int mi = 0; mi < 4; ++mi) {
                            aR[mi]  = MFMA(af[mi][0], bR0, aR[mi]);  aR[mi]  = MFMA(af[mi][1], bR1, aR[mi]);
                            aZ[mi]  = MFMA(af[mi][0], bZ0, aZ[mi]);  aZ[mi]  = MFMA(af[mi][1], bZ1, aZ[mi]);
                            aNh[mi] = MFMA(af[mi][0], bN0, aNh[mi]); aNh[mi] = MFMA(af[mi][1], bN1, aNh[mi]);
                        }
                    } else {
                        short8 bR0 = bglob(Wih, cB, DIM, 0, 0, lane);
                        short8 bR1 = bglob(Wih, cB, DIM, 0, 1, lane);
                        short8 bZ0 = bglob(Wih, 512 + cB, DIM, 0, 0, lane);
                        short8 bZ1 = bglob(Wih, 512 + cB, DIM, 0, 1, lane);
                        short8 bN0 = bglob(Wih, 1024 + cB, DIM, 0, 0, lane);
                        short8 bN1 = bglob(Wih, 1024 + cB, DIM, 0, 1, lane);
                        #pragma unroll
                        for (int mi = 0; mi < 4; ++mi) {
                            aR[mi]  = MFMA(af[mi][0], bR0, aR[mi]);  aR[mi]  = MFMA(af[mi][1], bR1, aR[mi]);
                            aZ[mi]  = MFMA(af[mi][0], bZ0, aZ[mi]);  aZ[mi]  = MFMA(af[mi][1], bZ1, aZ[mi]);
                            aNx[mi] = MFMA(af[mi][0], bN0, aNx[mi]); aNx[mi] = MFMA(af[mi][1], bN1, aNx[mi]);
                        }
                    }
                } else {
                    short8 g0 = bglob(Wp1, cB, HID, t * 64, 0, lane);
                    short8 g1 = bglob(Wp1, cB, HID, t * 64, 1, lane);
                    #pragma unroll
                    for (int mi = 0; mi < 4; ++mi) {
                        aR[mi] = MFMA(af[mi][0], g0, aR[mi]);
                        aR[mi] = MFMA(af[mi][1], g1, aR[mi]);
                    }
                }
            }
            if (isGRU) {
                float biR = bih[cB] + bhh[cB];
                float biZ = bih[512 + cB] + bhh[512 + cB];
                float bNx = bih[1024 + cB], bNh = bhh[1024 + cB];
                #pragma unroll
                for (int mi = 0; mi < 4; ++mi)
                    #pragma unroll
                    for (int ii = 0; ii < 4; ++ii) {
                        int row_l = wr * 64 + mi * 16 + ((lane >> 4) << 2) + ii;
                        int gr = idxk[r0t + row_l];
                        float rg = sigmoidf_(aR[mi][ii] + biR);
                        float zg = sigmoidf_(aZ[mi][ii] + biZ);
                        float ng = tanhf(aNx[mi][ii] + bNx + rg * (aNh[mi][ii] + bNh));
                        size_t o = (size_t)gr * HID + cB;
                        h[o] = (1.0f - zg) * ng + zg * h[o];
                    }
            } else {
                float bq = bp1[cB];
                #pragma unroll
                for (int mi = 0; mi < 4; ++mi)
                    #pragma unroll
                    for (int ii = 0; ii < 4; ++ii) {
                        int row_l = wr * 64 + mi * 16 + ((lane >> 4) << 2) + ii;
                        qb[(size_t)(r0t + row_l) * HID + cB] = f2bf(fmaxf(aR[mi][ii] + bq, 0.0f));
                    }
            }
        }
        grid.sync();
    }

    // final event's p+loss
    if (bid < 16)
        p_loss_task(KEV - 1, bid, tbuf, qb, Wp2, bp2, Xf, Mf, sums, tid, lane, w);
    grid.sync();
    if (bid == 0 && tid == 0) { out[0] = sums[0] / sums[1]; out[1] = 0.0f; }
}

__global__ __launch_bounds__(256) void f2b4_kernel(
    const float* __restrict__ s, ushort* __restrict__ d, int n4)
{
    int t = blockIdx.x * 256 + threadIdx.x;
    if (t >= n4) return;
    float4 v = ((const float4*)s)[t];
    ushort4 o; o.x = f2bf(v.x); o.y = f2bf(v.y); o.z = f2bf(v.z); o.w = f2bf(v.w);
    ((ushort4*)d)[t] = o;
}

extern "C" void kernel_launch(void* const* d_in, const int* in_sizes, int n_in,
                              void* d_out, int out_size, void* d_ws, size_t ws_size,
                              hipStream_t stream) {
    const float* X      = (const float*)d_in[3];
    const float* M      = (const float*)d_in[4];
    const int* batch_idx= (const int*)  d_in[5];
    const float* W_ode1 = (const float*)d_in[6];
    const float* b_ode1 = (const float*)d_in[7];
    const float* W_ode2 = (const float*)d_in[8];
    const float* b_ode2 = (const float*)d_in[9];
    const float* W_ih   = (const float*)d_in[10];
    const float* W_hh   = (const float*)d_in[11];
    const float* b_ih   = (const float*)d_in[12];
    const float* b_hh   = (const float*)d_in[13];
    const float* Wp1    = (const float*)d_in[14];
    const float* bp1    = (const float*)d_in[15];
    const float* Wp2    = (const float*)d_in[16];
    const float* bp2    = (const float*)d_in[17];
    float* out = (float*)d_out;

    float* ws    = (float*)d_ws;
    float* h     = ws;                                  // 4096*512 f32
    float* sums  = h + (size_t)BATCH * HID;             // 16 f32
    ushort* hb   = (ushort*)(sums + 16);                // 4096*512
    ushort* qb   = hb  + (size_t)BATCH * HID;           // 2048*512
    ushort* Xbb  = qb  + (size_t)NPER * HID;            // 25*2048*64
    ushort* W1b  = Xbb + (size_t)KEV * NPER * DIM;      // 512*512
    ushort* W2b  = W1b + (size_t)HID * HID;
    ushort* Wp1b = W2b + (size_t)HID * HID;
    ushort* Wp2b = Wp1b + (size_t)HID * HID;            // 128*512
    ushort* Wihb = Wp2b + (size_t)2 * DIM * HID;        // 1536*64
    ushort* Whhb = Wihb + (size_t)3 * HID * DIM;        // 1536*512

    hipMemsetAsync(h,    0, (size_t)BATCH * HID * sizeof(float), stream);
    hipMemsetAsync(sums, 0, 2 * sizeof(float), stream);

    dim3 blk(256);
    auto cvt = [&](const float* s, ushort* d, size_t n) {
        f2b4_kernel<<<dim3((unsigned)((n / 4 + 255) / 256)), blk, 0, stream>>>(s, d, (int)(n / 4));
    };
    cvt(W_ode1, W1b,  (size_t)HID * HID);
    cvt(W_ode2, W2b,  (size_t)HID * HID);
    cvt(Wp1,    Wp1b, (size_t)HID * HID);
    cvt(Wp2,    Wp2b, (size_t)2 * DIM * HID);
    cvt(W_ih,   Wihb, (size_t)3 * HID * DIM);
    cvt(W_hh,   Whhb, (size_t)3 * HID * HID);
    cvt(X,      Xbb,  (size_t)KEV * NPER * DIM);

    // cooperative persistent launch
    const float* Xf = X; const float* Mf = M; const int* bidx = batch_idx;
    const ushort* Xb_c = Xbb; const ushort* W1_c = W1b; const ushort* W2_c = W2b;
    const ushort* Wp1_c = Wp1b; const ushort* Wp2_c = Wp2b;
    const ushort* Wih_c = Wihb; const ushort* Whh_c = Whhb;
    const float* b1_c = b_ode1; const float* b2_c = b_ode2;
    const float* bih_c = b_ih; const float* bhh_c = b_hh;
    const float* bp1_c = bp1; const float* bp2_c = bp2;
    float* h_c = h; ushort* hb_c = hb; ushort* qb_c = qb;
    float* sums_c = sums; float* out_c = out;

    void* kargs[] = {
        (void*)&Xf, (void*)&Mf, (void*)&bidx, (void*)&Xb_c,
        (void*)&W1_c, (void*)&W2_c, (void*)&Wp1_c, (void*)&Wp2_c,
        (void*)&Wih_c, (void*)&Whh_c,
        (void*)&b1_c, (void*)&b2_c, (void*)&bih_c, (void*)&bhh_c,
        (void*)&bp1_c, (void*)&bp2_c,
        (void*)&h_c, (void*)&hb_c, (void*)&qb_c, (void*)&sums_c, (void*)&out_c
    };
    hipLaunchCooperativeKernel((const void*)persist, dim3(NBLK), dim3(NTHR),
                               kargs, 0, stream);
}

// Round 7
// 2982.584 us; speedup vs baseline: 2.0460x; 2.0460x over previous
//
#include <hip/hip_runtime.h>
#include <cstdint>
#include <cstddef>

#define BATCH 4096
#define DIM 64
#define HID 512
#define NPER 2048
#define KEV 25
#define DT_C 0.01f
#define LOG_SQRT_2PI_C 0.9189385332046727f

typedef __attribute__((ext_vector_type(8))) short short8;
typedef __attribute__((ext_vector_type(4))) float f32x4;

#define MFMA(a, b, c) __builtin_amdgcn_mfma_f32_16x16x32_bf16(a, b, c, 0, 0, 0)

__device__ __forceinline__ ushort f2bf(float f) {
    uint32_t u = __float_as_uint(f);
    u += 0x7FFF + ((u >> 16) & 1);
    return (ushort)(u >> 16);
}
__device__ __forceinline__ float sigmoidf_(float x) { return 1.0f / (1.0f + expf(-x)); }

__device__ __forceinline__ void gload_lds16(const ushort* g, ushort* l) {
    __builtin_amdgcn_global_load_lds(
        (const __attribute__((address_space(1))) void*)g,
        (__attribute__((address_space(3))) void*)l, 16, 0, 0);
}

// fragment read from [rows][64] LDS tile, XOR-swizzled 8-elem slots
__device__ __forceinline__ short8 frag64(const ushort* lds, int row, int ks, int lane) {
    int slot = ((ks << 2) + (lane >> 4)) ^ (row & 7);
    return *(const short8*)&lds[row * 64 + slot * 8];
}

// ---------------- ODE GEMM: 64x64 tile, dbuf LDS, 1 barrier / K-step --------
// MODE 0: Cb = bf16(tanh(v + bias))
// MODE 1: h += DT*(v + bias) (fp32 master), Cb = bf16(h)
template<int MODE>
__global__ __launch_bounds__(256) void ode_gemm(
    const ushort* __restrict__ A, const ushort* __restrict__ W,
    const float* __restrict__ bias, float* __restrict__ h, ushort* __restrict__ Cb)
{
    __shared__ __align__(16) ushort Alds[2][64 * 64];
    __shared__ __align__(16) ushort Blds[2][64 * 64];
    const int tid = threadIdx.x, lane = tid & 63, w = tid >> 6;
    const int wr = w >> 1, wc = w & 1;
    const int r0 = blockIdx.y * 64, c0 = blockIdx.x * 64;
    const int srow = lane >> 3;                 // 0..7
    const int sg = ((lane & 7) ^ srow) << 3;    // swizzled 16B slot in 64-elem row
    const size_t ga0 = (size_t)(r0 + w * 16 + srow) * HID;
    const size_t ga1 = (size_t)(r0 + w * 16 + 8 + srow) * HID;
    const size_t gb0 = (size_t)(c0 + w * 16 + srow) * HID;
    const size_t gb1 = (size_t)(c0 + w * 16 + 8 + srow) * HID;

    f32x4 acc[2][2] = {};

    #define STAGE(b, k0) do {                                      \
        gload_lds16(A + ga0 + (k0) + sg, &Alds[b][(w * 16) * 64]);     \
        gload_lds16(A + ga1 + (k0) + sg, &Alds[b][(w * 16 + 8) * 64]); \
        gload_lds16(W + gb0 + (k0) + sg, &Blds[b][(w * 16) * 64]);     \
        gload_lds16(W + gb1 + (k0) + sg, &Blds[b][(w * 16 + 8) * 64]); \
    } while (0)

    STAGE(0, 0);
    __syncthreads();
    int cur = 0;
    for (int t = 0; t < 8; ++t) {
        if (t < 7) STAGE(cur ^ 1, (t + 1) * 64);
        short8 af[2][2], bf[2][2];
        #pragma unroll
        for (int mi = 0; mi < 2; ++mi) {
            int r = wr * 32 + mi * 16 + (lane & 15);
            af[mi][0] = frag64(&Alds[cur][0], r, 0, lane);
            af[mi][1] = frag64(&Alds[cur][0], r, 1, lane);
        }
        #pragma unroll
        for (int ni = 0; ni < 2; ++ni) {
            int c = wc * 32 + ni * 16 + (lane & 15);
            bf[ni][0] = frag64(&Blds[cur][0], c, 0, lane);
            bf[ni][1] = frag64(&Blds[cur][0], c, 1, lane);
        }
        #pragma unroll
        for (int ks = 0; ks < 2; ++ks)
            #pragma unroll
            for (int mi = 0; mi < 2; ++mi)
                #pragma unroll
                for (int ni = 0; ni < 2; ++ni)
                    acc[mi][ni] = MFMA(af[mi][ks], bf[ni][ks], acc[mi][ni]);
        __syncthreads();
        cur ^= 1;
    }
    #undef STAGE

    #pragma unroll
    for (int mi = 0; mi < 2; ++mi)
        #pragma unroll
        for (int ni = 0; ni < 2; ++ni) {
            const int c = c0 + wc * 32 + ni * 16 + (lane & 15);
            const float bv = bias[c];
            #pragma unroll
            for (int ii = 0; ii < 4; ++ii) {
                const int r = r0 + wr * 32 + mi * 16 + ((lane >> 4) << 2) + ii;
                const size_t o = (size_t)r * HID + c;
                float v = acc[mi][ni][ii] + bv;
                if (MODE == 0) {
                    Cb[o] = f2bf(tanhf(v));
                } else {
                    float nh = h[o] + DT_C * v;
                    h[o] = nh; Cb[o] = f2bf(nh);
                }
            }
        }
}

// ---------------- E1: all event GEMMs in one dispatch ------------------------
// bx <  256 : q   = relu(hg Wp1^T + bp1)                 -> qb bf16
// 256..767  : rz  = sigmoid(hg Whh[0:1024]^T + X Wih[0:1024]^T + bih+bhh) -> f32
// 768..1023 : nh_ = hg Whh_n^T + bhh_n ; nx_ = X Wih_n^T + bih_n          -> f32
__global__ __launch_bounds__(256) void event_e1(
    const ushort* __restrict__ hb, const ushort* __restrict__ Xbk,
    const int* __restrict__ idx,
    const ushort* __restrict__ Wp1b, const float* __restrict__ bp1,
    const ushort* __restrict__ Whhb, const ushort* __restrict__ Wihb,
    const float* __restrict__ bih, const float* __restrict__ bhh,
    ushort* __restrict__ qb, float* __restrict__ rz,
    float* __restrict__ nh_, float* __restrict__ nx_)
{
    __shared__ __align__(16) ushort Alds[2][64 * 64];
    __shared__ __align__(16) ushort Blds[2][64 * 64];
    const int tid = threadIdx.x, lane = tid & 63, w = tid >> 6;
    const int wr = w >> 1, wc = w & 1;

    const int bx = blockIdx.x;
    int task, rt, ct;
    if (bx < 256)      { task = 0; rt = bx >> 3;          ct = bx & 7;  }
    else if (bx < 768) { task = 1; rt = (bx - 256) >> 4;  ct = (bx - 256) & 15; }
    else               { task = 2; rt = (bx - 768) >> 3;  ct = (bx - 768) & 7;  }
    const int r0t = rt * 64, c0 = ct * 64;
    const ushort* Bh = (task == 0) ? Wp1b : (task == 1 ? Whhb : Whhb + (size_t)1024 * HID);
    const ushort* Bx = (task == 1) ? Wihb : Wihb + (size_t)1024 * DIM;
    const bool TAIL = (task != 0);

    const int srow = lane >> 3;
    const int sg = ((lane & 7) ^ srow) << 3;
    const int ar0 = r0t + w * 16 + srow, ar1 = r0t + w * 16 + 8 + srow;
    const size_t ga0 = (size_t)idx[ar0] * HID;
    const size_t ga1 = (size_t)idx[ar1] * HID;
    const size_t gb0 = (size_t)(c0 + w * 16 + srow) * HID;
    const size_t gb1 = (size_t)(c0 + w * 16 + 8 + srow) * HID;

    f32x4 acc[2][2] = {}, accX[2][2] = {};

    #define STAGE_M(b, k0) do {                                          \
        gload_lds16(hb + ga0 + (k0) + sg, &Alds[b][(w * 16) * 64]);          \
        gload_lds16(hb + ga1 + (k0) + sg, &Alds[b][(w * 16 + 8) * 64]);      \
        gload_lds16(Bh + gb0 + (k0) + sg, &Blds[b][(w * 16) * 64]);          \
        gload_lds16(Bh + gb1 + (k0) + sg, &Blds[b][(w * 16 + 8) * 64]);      \
    } while (0)
    #define STAGE_T(b) do {                                                              \
        gload_lds16(Xbk + (size_t)ar0 * DIM + sg, &Alds[b][(w * 16) * 64]);                  \
        gload_lds16(Xbk + (size_t)ar1 * DIM + sg, &Alds[b][(w * 16 + 8) * 64]);              \
        gload_lds16(Bx + (size_t)(c0 + w * 16 + srow) * DIM + sg, &Blds[b][(w * 16) * 64]);  \
        gload_lds16(Bx + (size_t)(c0 + w * 16 + 8 + srow) * DIM + sg, &Blds[b][(w * 16 + 8) * 64]); \
    } while (0)

    STAGE_M(0, 0);
    __syncthreads();
    int cur = 0;
    for (int t = 0; t < 8; ++t) {
        if (t < 7) STAGE_M(cur ^ 1, (t + 1) * 64);
        else if (TAIL) STAGE_T(cur ^ 1);
        short8 af[2][2], bf[2][2];
        #pragma unroll
        for (int mi = 0; mi < 2; ++mi) {
            int r = wr * 32 + mi * 16 + (lane & 15);
            af[mi][0] = frag64(&Alds[cur][0], r, 0, lane);
            af[mi][1] = frag64(&Alds[cur][0], r, 1, lane);
        }
        #pragma unroll
        for (int ni = 0; ni < 2; ++ni) {
            int c = wc * 32 + ni * 16 + (lane & 15);
            bf[ni][0] = frag64(&Blds[cur][0], c, 0, lane);
            bf[ni][1] = frag64(&Blds[cur][0], c, 1, lane);
        }
        #pragma unroll
        for (int ks = 0; ks < 2; ++ks)
            #pragma unroll
            for (int mi = 0; mi < 2; ++mi)
                #pragma unroll
                for (int ni = 0; ni < 2; ++ni)
                    acc[mi][ni] = MFMA(af[mi][ks], bf[ni][ks], acc[mi][ni]);
        __syncthreads();
        cur ^= 1;
    }
    if (TAIL) {
        short8 af[2][2], bf[2][2];
        #pragma unroll
        for (int mi = 0; mi < 2; ++mi) {
            int r = wr * 32 + mi * 16 + (lane & 15);
            af[mi][0] = frag64(&Alds[cur][0], r, 0, lane);
            af[mi][1] = frag64(&Alds[cur][0], r, 1, lane);
        }
        #pragma unroll
        for (int ni = 0; ni < 2; ++ni) {
            int c = wc * 32 + ni * 16 + (lane & 15);
            bf[ni][0] = frag64(&Blds[cur][0], c, 0, lane);
            bf[ni][1] = frag64(&Blds[cur][0], c, 1, lane);
        }
        #pragma unroll
        for (int ks = 0; ks < 2; ++ks)
            #pragma unroll
            for (int mi = 0; mi < 2; ++mi)
                #pragma unroll
                for (int ni = 0; ni < 2; ++ni) {
                    f32x4& a = (task == 2) ? accX[mi][ni] : acc[mi][ni];
                    a = MFMA(af[mi][ks], bf[ni][ks], a);
                }
    }
    #undef STAGE_M
    #undef STAGE_T

    #pragma unroll
    for (int mi = 0; mi < 2; ++mi)
        #pragma unroll
        for (int ni = 0; ni < 2; ++ni) {
            const int c = c0 + wc * 32 + ni * 16 + (lane & 15);
            #pragma unroll
            for (int ii = 0; ii < 4; ++ii) {
                const int iobs = r0t + wr * 32 + mi * 16 + ((lane >> 4) << 2) + ii;
                float v = acc[mi][ni][ii];
                if (task == 0) {
                    qb[(size_t)iobs * HID + c] = f2bf(fmaxf(v + bp1[c], 0.0f));
                } else if (task == 1) {
                    rz[(size_t)iobs * 1024 + c] = sigmoidf_(v + bih[c] + bhh[c]);
                } else {
                    nh_[(size_t)iobs * HID + c] = v + bhh[1024 + c];
                    nx_[(size_t)iobs * HID + c] = accX[mi][ni][ii] + bih[1024 + c];
                }
            }
        }
}

__device__ __forceinline__ void block_atomic_sum(float v, float* acc) {
    __shared__ float red[4];
    #pragma unroll
    for (int off = 32; off > 0; off >>= 1) v += __shfl_down(v, off);
    int lane = threadIdx.x & 63, wid = threadIdx.x >> 6;
    if (lane == 0) red[wid] = v;
    __syncthreads();
    if (threadIdx.x == 0) atomicAdd(acc, red[0] + red[1] + red[2] + red[3]);
}

// ---------------- E2: p+loss (bx<32) and GRU combine+scatter (bx>=32) --------
__global__ __launch_bounds__(256) void event_e2(
    const ushort* __restrict__ qb, const ushort* __restrict__ Wp2b,
    const float* __restrict__ bp2, const float* __restrict__ Xk,
    const float* __restrict__ Mk, float* __restrict__ sums,
    const float* __restrict__ rz, const float* __restrict__ nh_,
    const float* __restrict__ nx_, const int* __restrict__ idx,
    float* __restrict__ h, ushort* __restrict__ hb)
{
    __shared__ __align__(16) ushort Alds[64 * 64];
    __shared__ __align__(16) ushort Blds[128 * 64];
    __shared__ float Plds[64 * 128];
    const int tid = threadIdx.x, lane = tid & 63, w = tid >> 6;

    if (blockIdx.x >= 32) {
        // GRU combine + scatter (256 blocks x 256 thr x 4 float4)
        const int gid = (blockIdx.x - 32) * 256 + tid;
        #pragma unroll
        for (int it = 0; it < 4; ++it) {
            int v = gid + it * 65536;           // vec4 id over 2048x512/4
            int row = v >> 7, j4 = (v & 127) << 2;
            float4 rr  = *(const float4*)&rz[(size_t)row * 1024 + j4];
            float4 zz  = *(const float4*)&rz[(size_t)row * 1024 + 512 + j4];
            float4 hnv = *(const float4*)&nh_[(size_t)row * HID + j4];
            float4 xnv = *(const float4*)&nx_[(size_t)row * HID + j4];
            size_t o = (size_t)idx[row] * HID + j4;
            float4 hv = *(const float4*)&h[o];
            float4 res; ushort4 ob;
            #define C1(c) { float n = tanhf(xnv.c + rr.c * hnv.c); \
                            res.c = (1.0f - zz.c) * n + zz.c * hv.c; ob.c = f2bf(res.c); }
            C1(x) C1(y) C1(z) C1(w)
            #undef C1
            *(float4*)&h[o] = res;
            *(ushort4*)&hb[o] = ob;
        }
        return;
    }

    // ---- p = q Wp2^T + bp2, fused NLL loss (32 blocks) ----
    const int wr = w >> 1, wc = w & 1;
    const int r0t = blockIdx.x * 64;
    const int arow = w * 16 + (lane >> 3);
    const int sg = ((lane & 7) ^ ((lane >> 3) & 7)) << 3;

    f32x4 acc[2][4] = {};
    for (int k0 = 0; k0 < HID; k0 += 64) {
        __syncthreads();
        gload_lds16(qb + (size_t)(r0t + arow) * HID + k0 + sg, &Alds[(w * 16) * 64]);
        gload_lds16(qb + (size_t)(r0t + arow + 8) * HID + k0 + sg, &Alds[(w * 16 + 8) * 64]);
        #pragma unroll
        for (int j = 0; j < 4; ++j) {
            int g = w * 4 + j;
            int rw = g * 8 + (lane >> 3);
            gload_lds16(Wp2b + (size_t)rw * HID + k0 + (((lane & 7) ^ (rw & 7)) << 3),
                        &Blds[g * 8 * 64]);
        }
        __syncthreads();
        short8 af[2][2], bf[4][2];
        #pragma unroll
        for (int mi = 0; mi < 2; ++mi) {
            int r = wr * 32 + mi * 16 + (lane & 15);
            af[mi][0] = frag64(Alds, r, 0, lane);
            af[mi][1] = frag64(Alds, r, 1, lane);
        }
        #pragma unroll
        for (int ni = 0; ni < 4; ++ni) {
            int c = wc * 64 + ni * 16 + (lane & 15);
            bf[ni][0] = frag64(Blds, c, 0, lane);
            bf[ni][1] = frag64(Blds, c, 1, lane);
        }
        #pragma unroll
        for (int ks = 0; ks < 2; ++ks)
            #pragma unroll
            for (int mi = 0; mi < 2; ++mi)
                #pragma unroll
                for (int ni = 0; ni < 4; ++ni)
                    acc[mi][ni] = MFMA(af[mi][ks], bf[ni][ks], acc[mi][ni]);
    }

    #pragma unroll
    for (int mi = 0; mi < 2; ++mi)
        #pragma unroll
        for (int ni = 0; ni < 4; ++ni) {
            int c = wc * 64 + ni * 16 + (lane & 15);
            float bv = bp2[c];
            #pragma unroll
            for (int ii = 0; ii < 4; ++ii) {
                int r = wr * 32 + mi * 16 + ((lane >> 4) << 2) + ii;
                Plds[r * 128 + c] = acc[mi][ni][ii] + bv;
            }
        }
    __syncthreads();

    float local = 0.0f;
    for (int t = tid; t < 64 * 64; t += 256) {
        int r = t >> 6, jj = t & 63;
        float mean = Plds[r * 128 + jj];
        float lv   = Plds[r * 128 + 64 + jj];
        int g = r0t + r;
        float err = (Xk[g * 64 + jj] - mean) * expf(-0.5f * lv);
        local += 0.5f * (err * err + lv + 2.0f * LOG_SQRT_2PI_C) * Mk[g * 64 + jj];
    }
    block_atomic_sum(local, sums);
}

__global__ __launch_bounds__(256) void f2b4_kernel(
    const float* __restrict__ s, ushort* __restrict__ d, int n4)
{
    int t = blockIdx.x * 256 + threadIdx.x;
    if (t >= n4) return;
    float4 v = ((const float4*)s)[t];
    ushort4 o; o.x = f2bf(v.x); o.y = f2bf(v.y); o.z = f2bf(v.z); o.w = f2bf(v.w);
    ((ushort4*)d)[t] = o;
}

__global__ __launch_bounds__(256) void msum_kernel(
    const float* __restrict__ M, int n, float* __restrict__ m_acc)
{
    float v = 0.0f;
    for (int t = blockIdx.x * 256 + threadIdx.x; t < n; t += gridDim.x * 256)
        v += M[t];
    block_atomic_sum(v, m_acc);
}

__global__ void finalize_kernel(const float* __restrict__ sums, float* __restrict__ out) {
    if (threadIdx.x == 0) { out[0] = sums[0] / sums[1]; out[1] = 0.0f; }
}

extern "C" void kernel_launch(void* const* d_in, const int* in_sizes, int n_in,
                              void* d_out, int out_size, void* d_ws, size_t ws_size,
                              hipStream_t stream) {
    const float* X      = (const float*)d_in[3];
    const float* M      = (const float*)d_in[4];
    const int* batch_idx= (const int*)  d_in[5];
    const float* W_ode1 = (const float*)d_in[6];
    const float* b_ode1 = (const float*)d_in[7];
    const float* W_ode2 = (const float*)d_in[8];
    const float* b_ode2 = (const float*)d_in[9];
    const float* W_ih   = (const float*)d_in[10];
    const float* W_hh   = (const float*)d_in[11];
    const float* b_ih   = (const float*)d_in[12];
    const float* b_hh   = (const float*)d_in[13];
    const float* Wp1    = (const float*)d_in[14];
    const float* bp1    = (const float*)d_in[15];
    const float* Wp2    = (const float*)d_in[16];
    const float* bp2    = (const float*)d_in[17];
    float* out = (float*)d_out;

    float* ws    = (float*)d_ws;
    float* h     = ws;                                  // 4096*512
    float* rz    = h   + (size_t)BATCH * HID;           // 2048*1024
    float* nh_   = rz  + (size_t)NPER * 1024;           // 2048*512
    float* nx_   = nh_ + (size_t)NPER * HID;            // 2048*512
    float* sums  = nx_ + (size_t)NPER * HID;            // 16
    ushort* hb   = (ushort*)(sums + 16);                // 4096*512
    ushort* qb   = hb  + (size_t)BATCH * HID;           // 2048*512
    ushort* Xb   = qb  + (size_t)NPER * HID;            // 25*2048*64
    ushort* W1b  = Xb  + (size_t)KEV * NPER * DIM;      // 512*512
    ushort* W2b  = W1b + (size_t)HID * HID;
    ushort* Wp1b = W2b + (size_t)HID * HID;
    ushort* Wp2b = Wp1b + (size_t)HID * HID;            // 128*512
    ushort* Wihb = Wp2b + (size_t)2 * DIM * HID;        // 1536*64
    ushort* Whhb = Wihb + (size_t)3 * HID * DIM;        // 1536*512

    hipMemsetAsync(h,    0, (size_t)BATCH * HID * sizeof(float), stream);
    hipMemsetAsync(hb,   0, (size_t)BATCH * HID * sizeof(ushort), stream);
    hipMemsetAsync(sums, 0, 2 * sizeof(float), stream);

    dim3 blk(256);
    auto cvt = [&](const float* s, ushort* d, size_t n) {
        f2b4_kernel<<<dim3((unsigned)((n / 4 + 255) / 256)), blk, 0, stream>>>(s, d, (int)(n / 4));
    };
    cvt(W_ode1, W1b,  (size_t)HID * HID);
    cvt(W_ode2, W2b,  (size_t)HID * HID);
    cvt(Wp1,    Wp1b, (size_t)HID * HID);
    cvt(Wp2,    Wp2b, (size_t)2 * DIM * HID);
    cvt(W_ih,   Wihb, (size_t)3 * HID * DIM);
    cvt(W_hh,   Whhb, (size_t)3 * HID * HID);
    cvt(X,      Xb,   (size_t)KEV * NPER * DIM);

    msum_kernel<<<1024, blk, 0, stream>>>(M, KEV * NPER * DIM, sums + 1);

    dim3 gOde(HID / 64, BATCH / 64);   // (8, 64) = 512 blocks

    for (int k = 0; k < KEV; ++k) {
        const float*  Xk  = X  + (size_t)k * NPER * DIM;
        const float*  Mk  = M  + (size_t)k * NPER * DIM;
        const ushort* Xbk = Xb + (size_t)k * NPER * DIM;
        const int*   idxk = batch_idx + (size_t)k * NPER;

        for (int s = 0; s < 2; ++s) {
            ode_gemm<0><<<gOde, blk, 0, stream>>>(hb,  W1b, b_ode1, nullptr, qb == nullptr ? nullptr : (ushort*)qb), // placeholder avoided below
            (void)0;
        }
        // (re-issue cleanly: the loop above must launch with correct args)
        // NOTE: corrected sequence:
        // step 1
        // -- see below
        break;
    }

    // ---- main event loop (clean) ----
    for (int k = 0; k < KEV; ++k) {
        const float*  Xk  = X  + (size_t)k * NPER * DIM;
        const float*  Mk  = M  + (size_t)k * NPER * DIM;
        const ushort* Xbk = Xb + (size_t)k * NPER * DIM;
        const int*   idxk = batch_idx + (size_t)k * NPER;
        ushort* tbb = qb;  // reuse qb? NO — qb needed by E2. Use separate buffer:
        tbb = Whhb + (size_t)3 * HID * HID;  // scratch bf16 after weights: 4096*512

        for (int s = 0; s < 2; ++s) {
            ode_gemm<0><<<gOde, blk, 0, stream>>>(hb,  W1b, b_ode1, nullptr, tbb);
            ode_gemm<1><<<gOde, blk, 0, stream>>>(tbb, W2b, b_ode2, h,       hb);
        }

        event_e1<<<dim3(1024), blk, 0, stream>>>(
            hb, Xbk, idxk, Wp1b, bp1, Whhb, Wihb, b_ih, b_hh, qb, rz, nh_, nx_);

        event_e2<<<dim3(288), blk, 0, stream>>>(
            qb, Wp2b, bp2, Xk, Mk, sums, rz, nh_, nx_, idxk, h, hb);
    }

    finalize_kernel<<<1, 64, 0, stream>>>(sums, out);
}

// Round 8
// 2380.665 us; speedup vs baseline: 2.5633x; 1.2528x over previous
//
#include <hip/hip_runtime.h>
#include <cstdint>
#include <cstddef>

#define BATCH 4096
#define DIM 64
#define HID 512
#define NPER 2048
#define KEV 25
#define DT_C 0.01f
#define LOG_SQRT_2PI_C 0.9189385332046727f

typedef __attribute__((ext_vector_type(8))) short short8;
typedef __attribute__((ext_vector_type(4))) float f32x4;

#define MFMA(a, b, c) __builtin_amdgcn_mfma_f32_16x16x32_bf16(a, b, c, 0, 0, 0)

__device__ __forceinline__ ushort f2bf(float f) {
    uint32_t u = __float_as_uint(f);
    u += 0x7FFF + ((u >> 16) & 1);
    return (ushort)(u >> 16);
}
__device__ __forceinline__ float sigmoidf_(float x) { return 1.0f / (1.0f + expf(-x)); }

__device__ __forceinline__ void gload_lds16(const ushort* g, ushort* l) {
    __builtin_amdgcn_global_load_lds(
        (const __attribute__((address_space(1))) void*)g,
        (__attribute__((address_space(3))) void*)l, 16, 0, 0);
}

__device__ __forceinline__ void wait_vm(int n) {
    if (n == 6)      asm volatile("s_waitcnt vmcnt(6)" ::: "memory");
    else if (n == 4) asm volatile("s_waitcnt vmcnt(4)" ::: "memory");
    else             asm volatile("s_waitcnt vmcnt(0)" ::: "memory");
}
#define BARRIER() __builtin_amdgcn_s_barrier()
#define SCHED0()  __builtin_amdgcn_sched_barrier(0)

// fragment read from [rows][64] LDS tile, XOR-swizzled 8-elem slots
__device__ __forceinline__ short8 frag64(const ushort* lds, int row, int ks, int lane) {
    int slot = ((ks << 2) + (lane >> 4)) ^ (row & 7);
    return *(const short8*)&lds[row * 64 + slot * 8];
}

// ---------------- ODE GEMM: 64x64 tile, depth-2 counted-vmcnt pipeline ------
// MODE 0: Cb = bf16(tanh(v + bias))
// MODE 1: h += DT*(v + bias) (fp32 master), Cb = bf16(h)
template<int MODE>
__global__ __launch_bounds__(256) void ode_gemm(
    const ushort* __restrict__ A, const ushort* __restrict__ W,
    const float* __restrict__ bias, float* __restrict__ h, ushort* __restrict__ Cb)
{
    __shared__ __align__(16) ushort Alds[2][64 * 64];
    __shared__ __align__(16) ushort Blds[2][64 * 64];
    const int tid = threadIdx.x, lane = tid & 63, w = tid >> 6;
    const int wr = w >> 1, wc = w & 1;
    const int r0 = blockIdx.y * 64, c0 = blockIdx.x * 64;
    const int srow = lane >> 3;
    const int sg = ((lane & 7) ^ srow) << 3;
    const size_t ga0 = (size_t)(r0 + w * 16 + srow) * HID;
    const size_t ga1 = (size_t)(r0 + w * 16 + 8 + srow) * HID;
    const size_t gb0 = (size_t)(c0 + w * 16 + srow) * HID;
    const size_t gb1 = (size_t)(c0 + w * 16 + 8 + srow) * HID;

    f32x4 acc[2][2] = {};

    #define STAGE(b, k0) do {                                          \
        gload_lds16(A + ga0 + (k0) + sg, &Alds[b][(w * 16) * 64]);         \
        gload_lds16(A + ga1 + (k0) + sg, &Alds[b][(w * 16 + 8) * 64]);     \
        gload_lds16(W + gb0 + (k0) + sg, &Blds[b][(w * 16) * 64]);         \
        gload_lds16(W + gb1 + (k0) + sg, &Blds[b][(w * 16 + 8) * 64]);     \
    } while (0)

    STAGE(0, 0);
    STAGE(1, 64);
    #pragma unroll
    for (int t = 0; t < 8; ++t) {
        wait_vm((t < 7) ? 4 : 0);      // panel t landed; panel t+1 stays in flight
        BARRIER();
        SCHED0();
        const ushort* Ab = &Alds[t & 1][0];
        const ushort* Bb = &Blds[t & 1][0];
        short8 af[2][2], bf[2][2];
        #pragma unroll
        for (int mi = 0; mi < 2; ++mi) {
            int r = wr * 32 + mi * 16 + (lane & 15);
            af[mi][0] = frag64(Ab, r, 0, lane);
            af[mi][1] = frag64(Ab, r, 1, lane);
        }
        #pragma unroll
        for (int ni = 0; ni < 2; ++ni) {
            int c = wc * 32 + ni * 16 + (lane & 15);
            bf[ni][0] = frag64(Bb, c, 0, lane);
            bf[ni][1] = frag64(Bb, c, 1, lane);
        }
        #pragma unroll
        for (int ks = 0; ks < 2; ++ks)
            #pragma unroll
            for (int mi = 0; mi < 2; ++mi)
                #pragma unroll
                for (int ni = 0; ni < 2; ++ni)
                    acc[mi][ni] = MFMA(af[mi][ks], bf[ni][ks], acc[mi][ni]);
        SCHED0();
        BARRIER();                     // buf[t] consumed by all waves
        if (t + 2 < 8) STAGE(t & 1, (t + 2) * 64);
    }
    #undef STAGE

    #pragma unroll
    for (int mi = 0; mi < 2; ++mi)
        #pragma unroll
        for (int ni = 0; ni < 2; ++ni) {
            const int c = c0 + wc * 32 + ni * 16 + (lane & 15);
            const float bv = bias[c];
            #pragma unroll
            for (int ii = 0; ii < 4; ++ii) {
                const int r = r0 + wr * 32 + mi * 16 + ((lane >> 4) << 2) + ii;
                const size_t o = (size_t)r * HID + c;
                float v = acc[mi][ni][ii] + bv;
                if (MODE == 0) {
                    Cb[o] = f2bf(tanhf(v));
                } else {
                    float nh = h[o] + DT_C * v;
                    h[o] = nh; Cb[o] = f2bf(nh);
                }
            }
        }
}

// ---------------- event GEMM: A gathered from hb[idx]; same pipeline --------
// MODE 0: q = relu(. Wp1^T + bp1) -> qb bf16                    (NT=8)
// MODE 1: rz = sigmoid(concat-K + bih + bhh) -> fp32            (NT=9, tail->acc)
// MODE 2: n-gate + combine + scatter into h                     (NT=9, tail->accX)
template<int MODE>
__global__ __launch_bounds__(256) void event_gemm(
    const ushort* __restrict__ hb, const ushort* __restrict__ Xbk,
    const int* __restrict__ idx,
    const ushort* __restrict__ Bh, const ushort* __restrict__ Bx,
    const float* __restrict__ bias_i, const float* __restrict__ bias_h,
    float* __restrict__ rz, ushort* __restrict__ qb, float* __restrict__ h)
{
    __shared__ __align__(16) ushort Alds[2][64 * 64];
    __shared__ __align__(16) ushort Blds[2][64 * 64];
    const int tid = threadIdx.x, lane = tid & 63, w = tid >> 6;
    const int wr = w >> 1, wc = w & 1;
    const int r0t = blockIdx.y * 64;
    const int c0t = blockIdx.x * 64;
    const int NT = (MODE == 0) ? 8 : 9;

    const int srow = lane >> 3;
    const int sg = ((lane & 7) ^ srow) << 3;
    const int ar0 = r0t + w * 16 + srow, ar1 = r0t + w * 16 + 8 + srow;
    const size_t ga0 = (size_t)idx[ar0] * HID;
    const size_t ga1 = (size_t)idx[ar1] * HID;
    const size_t gb0 = (size_t)(c0t + w * 16 + srow) * HID;
    const size_t gb1 = (size_t)(c0t + w * 16 + 8 + srow) * HID;

    f32x4 acc[2][2] = {}, accX[2][2] = {};

    #define STAGE_P(b, p) do {                                                       \
        if ((p) < 8) {                                                               \
            gload_lds16(hb + ga0 + (p) * 64 + sg, &Alds[b][(w * 16) * 64]);              \
            gload_lds16(hb + ga1 + (p) * 64 + sg, &Alds[b][(w * 16 + 8) * 64]);          \
            gload_lds16(Bh + gb0 + (p) * 64 + sg, &Blds[b][(w * 16) * 64]);              \
            gload_lds16(Bh + gb1 + (p) * 64 + sg, &Blds[b][(w * 16 + 8) * 64]);          \
        } else {                                                                     \
            gload_lds16(Xbk + (size_t)ar0 * DIM + sg, &Alds[b][(w * 16) * 64]);          \
            gload_lds16(Xbk + (size_t)ar1 * DIM + sg, &Alds[b][(w * 16 + 8) * 64]);      \
            gload_lds16(Bx + (size_t)(c0t + w * 16 + srow) * DIM + sg,                   \
                        &Blds[b][(w * 16) * 64]);                                        \
            gload_lds16(Bx + (size_t)(c0t + w * 16 + 8 + srow) * DIM + sg,               \
                        &Blds[b][(w * 16 + 8) * 64]);                                    \
        }                                                                            \
    } while (0)

    STAGE_P(0, 0);
    STAGE_P(1, 1);
    #pragma unroll
    for (int t = 0; t < 9; ++t) {
        if (t >= NT) break;
        wait_vm((t + 1 < NT) ? 4 : 0);
        BARRIER();
        SCHED0();
        const ushort* Ab = &Alds[t & 1][0];
        const ushort* Bb = &Blds[t & 1][0];
        short8 af[2][2], bf[2][2];
        #pragma unroll
        for (int mi = 0; mi < 2; ++mi) {
            int r = wr * 32 + mi * 16 + (lane & 15);
            af[mi][0] = frag64(Ab, r, 0, lane);
            af[mi][1] = frag64(Ab, r, 1, lane);
        }
        #pragma unroll
        for (int ni = 0; ni < 2; ++ni) {
            int c = wc * 32 + ni * 16 + (lane & 15);
            bf[ni][0] = frag64(Bb, c, 0, lane);
            bf[ni][1] = frag64(Bb, c, 1, lane);
        }
        const bool toX = (MODE == 2) && (t == 8);
        #pragma unroll
        for (int ks = 0; ks < 2; ++ks)
            #pragma unroll
            for (int mi = 0; mi < 2; ++mi)
                #pragma unroll
                for (int ni = 0; ni < 2; ++ni) {
                    f32x4& a = toX ? accX[mi][ni] : acc[mi][ni];
                    a = MFMA(af[mi][ks], bf[ni][ks], a);
                }
        SCHED0();
        BARRIER();
        if (t + 2 < NT) STAGE_P(t & 1, t + 2);
    }
    #undef STAGE_P

    #pragma unroll
    for (int mi = 0; mi < 2; ++mi)
        #pragma unroll
        for (int ni = 0; ni < 2; ++ni) {
            const int c = c0t + wc * 32 + ni * 16 + (lane & 15);
            #pragma unroll
            for (int ii = 0; ii < 4; ++ii) {
                const int iobs = r0t + wr * 32 + mi * 16 + ((lane >> 4) << 2) + ii;
                float v = acc[mi][ni][ii];
                if (MODE == 0) {
                    qb[(size_t)iobs * HID + c] = f2bf(fmaxf(v + bias_h[c], 0.0f));
                } else if (MODE == 1) {
                    rz[(size_t)iobs * 1024 + c] = sigmoidf_(v + bias_i[c] + bias_h[c]);
                } else {
                    float vh = v + bias_h[c];
                    float vx = accX[mi][ni][ii] + bias_i[c];
                    float r = rz[(size_t)iobs * 1024 + c];
                    float z = rz[(size_t)iobs * 1024 + 512 + c];
                    float n = tanhf(vx + r * vh);
                    size_t o = (size_t)idx[iobs] * HID + c;
                    h[o] = (1.0f - z) * n + z * h[o];
                }
            }
        }
}

// refresh bf16 shadow of GRU-updated rows
__global__ __launch_bounds__(256) void scatter_b16(
    const float* __restrict__ h, const int* __restrict__ idx, ushort* __restrict__ hb)
{
    int t = blockIdx.x * 256 + threadIdx.x;   // over NPER*HID/8
    int i = t >> 6, j8 = (t & 63) << 3;
    size_t o = (size_t)idx[i] * HID + j8;
    float4 a = *(const float4*)&h[o];
    float4 b = *(const float4*)&h[o + 4];
    ushort ob[8] = {f2bf(a.x), f2bf(a.y), f2bf(a.z), f2bf(a.w),
                    f2bf(b.x), f2bf(b.y), f2bf(b.z), f2bf(b.w)};
    *(ushort4*)&hb[o]     = *(ushort4*)&ob[0];
    *(ushort4*)&hb[o + 4] = *(ushort4*)&ob[4];
}

__device__ __forceinline__ void block_atomic_sum(float v, float* acc) {
    __shared__ float red[4];
    #pragma unroll
    for (int off = 32; off > 0; off >>= 1) v += __shfl_down(v, off);
    int lane = threadIdx.x & 63, wid = threadIdx.x >> 6;
    if (lane == 0) red[wid] = v;
    __syncthreads();
    if (threadIdx.x == 0) atomicAdd(acc, red[0] + red[1] + red[2] + red[3]);
}

// ---------------- p = q Wp2^T + bp2 fused with NLL loss, pipelined ----------
__global__ __launch_bounds__(256) void p_loss(
    const ushort* __restrict__ qb, const ushort* __restrict__ Wp2b,
    const float* __restrict__ bp2, const float* __restrict__ Xk,
    const float* __restrict__ Mk, float* __restrict__ loss_acc)
{
    __shared__ __align__(16) ushort Alds[2][64 * 64];
    __shared__ __align__(16) ushort Blds[2][128 * 64];
    __shared__ float Plds[64 * 128];
    const int tid = threadIdx.x, lane = tid & 63, w = tid >> 6;
    const int wr = w >> 1, wc = w & 1;
    const int r0t = blockIdx.x * 64;
    const int arow = w * 16 + (lane >> 3);
    const int sg = ((lane & 7) ^ ((lane >> 3) & 7)) << 3;

    #define STAGE_PL(b, k0) do {                                                        \
        gload_lds16(qb + (size_t)(r0t + arow) * HID + (k0) + sg, &Alds[b][(w * 16) * 64]);  \
        gload_lds16(qb + (size_t)(r0t + arow + 8) * HID + (k0) + sg,                        \
                    &Alds[b][(w * 16 + 8) * 64]);                                           \
        _Pragma("unroll")                                                                   \
        for (int j_ = 0; j_ < 4; ++j_) {                                                    \
            int g_ = w * 4 + j_;                                                            \
            int rw_ = g_ * 8 + (lane >> 3);                                                 \
            gload_lds16(Wp2b + (size_t)rw_ * HID + (k0) + (((lane & 7) ^ (rw_ & 7)) << 3),  \
                        &Blds[b][g_ * 8 * 64]);                                             \
        }                                                                               \
    } while (0)

    f32x4 acc[2][4] = {};
    STAGE_PL(0, 0);
    STAGE_PL(1, 64);
    #pragma unroll
    for (int t = 0; t < 8; ++t) {
        wait_vm((t < 7) ? 6 : 0);
        BARRIER();
        SCHED0();
        const ushort* Ab = &Alds[t & 1][0];
        const ushort* Bb = &Blds[t & 1][0];
        short8 af[2][2], bf[4][2];
        #pragma unroll
        for (int mi = 0; mi < 2; ++mi) {
            int r = wr * 32 + mi * 16 + (lane & 15);
            af[mi][0] = frag64(Ab, r, 0, lane);
            af[mi][1] = frag64(Ab, r, 1, lane);
        }
        #pragma unroll
        for (int ni = 0; ni < 4; ++ni) {
            int c = wc * 64 + ni * 16 + (lane & 15);
            bf[ni][0] = frag64(Bb, c, 0, lane);
            bf[ni][1] = frag64(Bb, c, 1, lane);
        }
        #pragma unroll
        for (int ks = 0; ks < 2; ++ks)
            #pragma unroll
            for (int mi = 0; mi < 2; ++mi)
                #pragma unroll
                for (int ni = 0; ni < 4; ++ni)
                    acc[mi][ni] = MFMA(af[mi][ks], bf[ni][ks], acc[mi][ni]);
        SCHED0();
        BARRIER();
        if (t + 2 < 8) STAGE_PL(t & 1, (t + 2) * 64);
    }
    #undef STAGE_PL

    #pragma unroll
    for (int mi = 0; mi < 2; ++mi)
        #pragma unroll
        for (int ni = 0; ni < 4; ++ni) {
            int c = wc * 64 + ni * 16 + (lane & 15);
            float bv = bp2[c];
            #pragma unroll
            for (int ii = 0; ii < 4; ++ii) {
                int r = wr * 32 + mi * 16 + ((lane >> 4) << 2) + ii;
                Plds[r * 128 + c] = acc[mi][ni][ii] + bv;
            }
        }
    __syncthreads();

    float local = 0.0f;
    for (int t = tid; t < 64 * 64; t += 256) {
        int r = t >> 6, jj = t & 63;
        float mean = Plds[r * 128 + jj];
        float lv   = Plds[r * 128 + 64 + jj];
        int g = r0t + r;
        float err = (Xk[g * 64 + jj] - mean) * expf(-0.5f * lv);
        local += 0.5f * (err * err + lv + 2.0f * LOG_SQRT_2PI_C) * Mk[g * 64 + jj];
    }
    block_atomic_sum(local, loss_acc);
}

__global__ __launch_bounds__(256) void f2b4_kernel(
    const float* __restrict__ s, ushort* __restrict__ d, int n4)
{
    int t = blockIdx.x * 256 + threadIdx.x;
    if (t >= n4) return;
    float4 v = ((const float4*)s)[t];
    ushort4 o; o.x = f2bf(v.x); o.y = f2bf(v.y); o.z = f2bf(v.z); o.w = f2bf(v.w);
    ((ushort4*)d)[t] = o;
}

__global__ __launch_bounds__(256) void msum_kernel(
    const float* __restrict__ M, int n, float* __restrict__ m_acc)
{
    float v = 0.0f;
    for (int t = blockIdx.x * 256 + threadIdx.x; t < n; t += gridDim.x * 256)
        v += M[t];
    block_atomic_sum(v, m_acc);
}

__global__ void finalize_kernel(const float* __restrict__ sums, float* __restrict__ out) {
    if (threadIdx.x == 0) { out[0] = sums[0] / sums[1]; out[1] = 0.0f; }
}

extern "C" void kernel_launch(void* const* d_in, const int* in_sizes, int n_in,
                              void* d_out, int out_size, void* d_ws, size_t ws_size,
                              hipStream_t stream) {
    const float* X      = (const float*)d_in[3];
    const float* M      = (const float*)d_in[4];
    const int* batch_idx= (const int*)  d_in[5];
    const float* W_ode1 = (const float*)d_in[6];
    const float* b_ode1 = (const float*)d_in[7];
    const float* W_ode2 = (const float*)d_in[8];
    const float* b_ode2 = (const float*)d_in[9];
    const float* W_ih   = (const float*)d_in[10];
    const float* W_hh   = (const float*)d_in[11];
    const float* b_ih   = (const float*)d_in[12];
    const float* b_hh   = (const float*)d_in[13];
    const float* Wp1    = (const float*)d_in[14];
    const float* bp1    = (const float*)d_in[15];
    const float* Wp2    = (const float*)d_in[16];
    const float* bp2    = (const float*)d_in[17];
    float* out = (float*)d_out;

    float* ws   = (float*)d_ws;
    float* h    = ws;                                   // 4096*512
    float* rz   = h  + (size_t)BATCH * HID;             // 2048*1024
    float* sums = rz + (size_t)NPER * 1024;             // 16
    ushort* hb   = (ushort*)(sums + 16);                // 4096*512
    ushort* tbb  = hb   + (size_t)BATCH * HID;          // 4096*512
    ushort* qb   = tbb  + (size_t)BATCH * HID;          // 2048*512
    ushort* Xb   = qb   + (size_t)NPER * HID;           // 25*2048*64
    ushort* W1b  = Xb   + (size_t)KEV * NPER * DIM;     // 512*512
    ushort* W2b  = W1b  + (size_t)HID * HID;
    ushort* Wp1b = W2b  + (size_t)HID * HID;
    ushort* Wp2b = Wp1b + (size_t)HID * HID;            // 128*512
    ushort* Wihb = Wp2b + (size_t)2 * DIM * HID;        // 1536*64
    ushort* Whhb = Wihb + (size_t)(3 * HID) * DIM;      // 1536*512

    hipMemsetAsync(h,    0, (size_t)BATCH * HID * sizeof(float), stream);
    hipMemsetAsync(hb,   0, (size_t)BATCH * HID * sizeof(ushort), stream);
    hipMemsetAsync(sums, 0, 2 * sizeof(float), stream);

    dim3 blk(256);
    auto cvt = [&](const float* s, ushort* d, size_t n) {
        f2b4_kernel<<<dim3((unsigned)((n / 4 + 255) / 256)), blk, 0, stream>>>(s, d, (int)(n / 4));
    };
    cvt(W_ode1, W1b,  (size_t)HID * HID);
    cvt(W_ode2, W2b,  (size_t)HID * HID);
    cvt(Wp1,    Wp1b, (size_t)HID * HID);
    cvt(Wp2,    Wp2b, (size_t)2 * DIM * HID);
    cvt(W_ih,   Wihb, (size_t)3 * HID * DIM);
    cvt(W_hh,   Whhb, (size_t)3 * HID * HID);
    cvt(X,      Xb,   (size_t)KEV * NPER * DIM);

    msum_kernel<<<1024, blk, 0, stream>>>(M, KEV * NPER * DIM, sums + 1);

    dim3 gOde(HID / 64, BATCH / 64);   // (8, 64) = 512 blocks

    for (int k = 0; k < KEV; ++k) {
        const float*  Xk  = X  + (size_t)k * NPER * DIM;
        const float*  Mk  = M  + (size_t)k * NPER * DIM;
        const ushort* Xbk = Xb + (size_t)k * NPER * DIM;
        const int*   idxk = batch_idx + (size_t)k * NPER;

        for (int s = 0; s < 2; ++s) {
            ode_gemm<0><<<gOde, blk, 0, stream>>>(hb,  W1b, b_ode1, nullptr, tbb);
            ode_gemm<1><<<gOde, blk, 0, stream>>>(tbb, W2b, b_ode2, h,       hb);
        }

        // head: q = relu(hg Wp1^T + bp1); then p+loss fused
        event_gemm<0><<<dim3(8, 32), blk, 0, stream>>>(
            hb, nullptr, idxk, Wp1b, nullptr, nullptr, bp1, nullptr, qb, nullptr);
        p_loss<<<32, blk, 0, stream>>>(qb, Wp2b, bp2, Xk, Mk, sums);

        // GRU: rz (concat-K), then n-gate + combine + scatter, then bf16 refresh
        event_gemm<1><<<dim3(16, 32), blk, 0, stream>>>(
            hb, Xbk, idxk, Whhb, Wihb, b_ih, b_hh, rz, nullptr, nullptr);
        event_gemm<2><<<dim3(8, 32), blk, 0, stream>>>(
            hb, Xbk, idxk, Whhb + (size_t)1024 * HID, Wihb + (size_t)1024 * DIM,
            b_ih + 1024, b_hh + 1024, rz, nullptr, h);
        scatter_b16<<<NPER * HID / 8 / 256, blk, 0, stream>>>(h, idxk, hb);
    }

    finalize_kernel<<<1, 64, 0, stream>>>(sums, out);
}